// Round 4
// baseline (395.124 us; speedup 1.0000x reference)
//
#include <hip/hip_runtime.h>
#include <hip/hip_bf16.h>

#define BB 4      // batch
#define SS 1023   // source length = 2T-1
#define TT 512    // window length
#define CC 1024   // embed dim
#define DD 64     // head size
#define NROW (BB*SS)    // 4092
#define MT 16           // proj rows per block
#define KB 128          // proj K chunk
#define NCHUNK (CC/KB)  // 8
#define WT 4            // attn queries per block

typedef float f4 __attribute__((ext_vector_type(4)));

// ---------------------------------------------------------------------------
// Kernel 1: projections as register-tiled GEMM.
// 256 blocks x 256 threads. Block computes MT=16 rows x 192 cols (k|v|q).
// Wave wv owns rows m0=4*wv..m0+3; lane d owns output col d of each proj.
// K streamed in KB=128 chunks through double-buffered LDS (reg-prefetched).
// k stored transposed kT[d][row] for coalesced attn reads.
// ---------------------------------------------------------------------------
__global__ __launch_bounds__(256) void proj_kernel(
    const float* __restrict__ x,
    const float* __restrict__ Wk,
    const float* __restrict__ Wv,
    const float* __restrict__ Wq,
    float* __restrict__ kT,     // [DD][NROW]
    float* __restrict__ vbuf,   // [NROW][DD]
    float* __restrict__ qbuf)   // [BB*TT][DD]
{
    __shared__ __align__(16) float xs[2][MT][KB];   // 16 KB

    const int tid = threadIdx.x;
    const int bs0 = blockIdx.x * MT;
    const int d   = tid & 63;
    const int wv  = tid >> 6;
    const int m0  = wv * 4;

    const int s0 = bs0 % SS;
    const bool needq = (s0 >= TT - MT);   // any row of this block has s >= TT-1

    // staging: 512 float4 per chunk; thread covers flat idx tid and tid+256
    const f4* sptr[2];
    {
#pragma unroll
        for (int j = 0; j < 2; ++j) {
            const int idx  = tid + j * 256;
            const int row  = idx >> 5;          // 32 float4 per 128-float row
            const int col4 = idx & 31;
            int g = bs0 + row; if (g > NROW - 1) g = NROW - 1;
            sptr[j] = (const f4*)(x + (size_t)g * CC) + col4;
        }
    }

    f4 pre0 = sptr[0][0];
    f4 pre1 = sptr[1][0];

    float acc[3][4];
#pragma unroll
    for (int p = 0; p < 3; ++p)
#pragma unroll
        for (int mm = 0; mm < 4; ++mm) acc[p][mm] = 0.f;

    int buf = 0;
    for (int ch = 0; ch < NCHUNK; ++ch) {
        ((f4*)xs[buf])[tid]       = pre0;
        ((f4*)xs[buf])[tid + 256] = pre1;
        __syncthreads();

        if (ch + 1 < NCHUNK) {                 // prefetch next chunk
            pre0 = sptr[0][(ch + 1) * (KB / 4)];
            pre1 = sptr[1][(ch + 1) * (KB / 4)];
        }

        const int c0 = ch * KB;
        const float* wkp = Wk + (size_t)c0 * DD + d;
        const float* wvp = Wv + (size_t)c0 * DD + d;
        const float* wqp = Wq + (size_t)c0 * DD + d;

        for (int k4 = 0; k4 < KB / 4; ++k4) {
            f4 xv[4];
#pragma unroll
            for (int mm = 0; mm < 4; ++mm)
                xv[mm] = *(const f4*)&xs[buf][m0 + mm][k4 * 4];
#pragma unroll
            for (int kk = 0; kk < 4; ++kk) {
                const int cl = k4 * 4 + kk;
                const float wk = wkp[cl * DD];
                const float wl = wvp[cl * DD];
#pragma unroll
                for (int mm = 0; mm < 4; ++mm) {
                    acc[0][mm] = fmaf(xv[mm][kk], wk, acc[0][mm]);
                    acc[1][mm] = fmaf(xv[mm][kk], wl, acc[1][mm]);
                }
                if (needq) {
                    const float wq = wqp[cl * DD];
#pragma unroll
                    for (int mm = 0; mm < 4; ++mm)
                        acc[2][mm] = fmaf(xv[mm][kk], wq, acc[2][mm]);
                }
            }
        }
        __syncthreads();
        buf ^= 1;
    }

    // stores (no cross-wave reduction needed: each thread did full K)
#pragma unroll
    for (int mm = 0; mm < 4; ++mm) {
        const int bs = bs0 + m0 + mm;
        if (bs <= NROW - 1) {
            kT[(size_t)d * NROW + bs] = acc[0][mm];
            vbuf[(size_t)bs * DD + d] = acc[1][mm];
            const int b = bs / SS, s = bs % SS;
            if (needq && s >= TT - 1)
                qbuf[((size_t)b * TT + (s - (TT - 1))) * DD + d] = acc[2][mm];
        }
    }
}

// ---------------------------------------------------------------------------
// Kernel 2: attention, WT=4 queries per block (512 blocks x 256 threads).
// Phase 1: thread owns t in {tid, tid+256}; sliding k regs serve all 4 m;
//          bias folded in: logit[m][t] = sum_d q[m][d]*(k[w0+m+t][d]+bias[d][t])
// Softmax: wave wv reduces row m=wv.
// Phase 2: wave wv covers t-range [128wv,128wv+128); sliding v regs serve 4 m.
// ---------------------------------------------------------------------------
__global__ __launch_bounds__(256) void attn_kernel(
    const float* __restrict__ kT,     // [DD][NROW]
    const float* __restrict__ vbuf,   // [NROW][DD]
    const float* __restrict__ qbuf,   // [BB*TT][DD]
    const float* __restrict__ bias,   // [DD][TT]
    float* __restrict__ out)          // [BB*TT][DD]
{
    __shared__ __align__(16) float qsT[DD][WT];       // 1 KB  [d][m]
    __shared__ float logit[WT][TT];                   // 8 KB
    __shared__ __align__(16) float weiT[TT][WT];      // 8 KB  [t][m]
    __shared__ float invs[WT];
    __shared__ float partial[4][WT][DD];              // 4 KB

    const int tid  = threadIdx.x;
    const int blk  = blockIdx.x;
    const int b    = blk >> 7;          // 128 blocks per batch
    const int w0   = (blk & 127) * WT;
    const int lane = tid & 63;
    const int wv   = tid >> 6;

    // load q tile transposed
    qsT[tid & 63][tid >> 6] = qbuf[((size_t)b * TT + w0 + (tid >> 6)) * DD + (tid & 63)];
    __syncthreads();

    // ---- phase 1: logits ----
    float accA[WT], accB[WT];
#pragma unroll
    for (int m = 0; m < WT; ++m) { accA[m] = 0.f; accB[m] = 0.f; }

    const size_t koff = (size_t)b * SS + w0;
#pragma unroll 2
    for (int d2 = 0; d2 < DD; ++d2) {
        const float* kr = kT + (size_t)d2 * NROW + koff;
        const float b0 = bias[d2 * TT + tid];
        const float b1 = bias[d2 * TT + tid + 256];
        const f4 qv = *(const f4*)&qsT[d2][0];
        float ka[WT + 0], kb[WT + 0];
#pragma unroll
        for (int m = 0; m < WT; ++m) {
            ka[m] = kr[tid + m];
            kb[m] = kr[tid + 256 + m];
        }
#pragma unroll
        for (int m = 0; m < WT; ++m) {
            accA[m] = fmaf(qv[m], ka[m] + b0, accA[m]);
            accB[m] = fmaf(qv[m], kb[m] + b1, accB[m]);
        }
    }
#pragma unroll
    for (int m = 0; m < WT; ++m) {
        logit[m][tid]       = accA[m];
        logit[m][tid + 256] = accB[m];
    }
    __syncthreads();

    // ---- softmax: wave wv owns row wv ----
    {
        const float* row = logit[wv];
        float r[8];
        float mx = -1e30f;
#pragma unroll
        for (int j = 0; j < 8; ++j) {
            r[j] = row[lane + 64 * j];
            mx = fmaxf(mx, r[j]);
        }
#pragma unroll
        for (int off = 1; off < 64; off <<= 1)
            mx = fmaxf(mx, __shfl_xor(mx, off, 64));
        float sum = 0.f;
#pragma unroll
        for (int j = 0; j < 8; ++j) {
            const float e = __expf(r[j] - mx);
            weiT[lane + 64 * j][wv] = e;
            sum += e;
        }
#pragma unroll
        for (int off = 1; off < 64; off <<= 1)
            sum += __shfl_xor(sum, off, 64);
        if (lane == 0) invs[wv] = 1.f / sum;
    }
    __syncthreads();

    // ---- phase 2: PV with sliding v registers ----
    {
        const int t0r = wv * 128;
        const float* vb = vbuf + ((size_t)b * SS + w0 + t0r) * DD + lane;
        float pacc[WT];
#pragma unroll
        for (int m = 0; m < WT; ++m) pacc[m] = 0.f;

        float v0 = vb[0 * DD], v1 = vb[1 * DD], v2 = vb[2 * DD];
#pragma unroll 4
        for (int t = 0; t < 128; ++t) {
            const float v3 = vb[(size_t)(t + 3) * DD];
            const f4 wv4 = *(const f4*)&weiT[t0r + t][0];
            pacc[0] = fmaf(wv4[0], v0, pacc[0]);
            pacc[1] = fmaf(wv4[1], v1, pacc[1]);
            pacc[2] = fmaf(wv4[2], v2, pacc[2]);
            pacc[3] = fmaf(wv4[3], v3, pacc[3]);
            v0 = v1; v1 = v2; v2 = v3;
        }
#pragma unroll
        for (int m = 0; m < WT; ++m) partial[wv][m][lane] = pacc[m];
    }
    __syncthreads();

    // ---- final reduce + store ----
    {
        const int m = tid >> 6, dd = tid & 63;
        const float o = (partial[0][m][dd] + partial[1][m][dd] +
                         partial[2][m][dd] + partial[3][m][dd]) * invs[m];
        out[((size_t)b * TT + w0 + m) * DD + dd] = o;
    }
}

// ---------------------------------------------------------------------------
extern "C" void kernel_launch(void* const* d_in, const int* in_sizes, int n_in,
                              void* d_out, int out_size, void* d_ws, size_t ws_size,
                              hipStream_t stream) {
    const float* x    = (const float*)d_in[0];
    const float* Wk   = (const float*)d_in[1];
    const float* Wv   = (const float*)d_in[2];
    const float* Wq   = (const float*)d_in[3];
    const float* bias = (const float*)d_in[4];
    float* out = (float*)d_out;

    float* kT   = (float*)d_ws;                     // DD*NROW
    float* vbuf = kT + (size_t)DD * NROW;           // NROW*DD
    float* qbuf = vbuf + (size_t)NROW * DD;         // BB*TT*DD

    proj_kernel<<<(NROW + MT - 1) / MT, 256, 0, stream>>>(x, Wk, Wv, Wq, kT, vbuf, qbuf);
    attn_kernel<<<BB * TT / WT, 256, 0, stream>>>(kT, vbuf, qbuf, bias, out);
}

// Round 5
// 146.358 us; speedup vs baseline: 2.6997x; 2.6997x over previous
//
#include <hip/hip_runtime.h>
#include <hip/hip_bf16.h>

#define BB 4      // batch
#define SS 1023   // source length = 2T-1
#define TT 512    // window length
#define CC 1024   // embed dim
#define DD 64     // head size
#define NROW (BB*SS)    // 4092
#define PR 8            // proj rows per block
#define PBLOCKS ((NROW + PR - 1) / PR)   // 512

typedef float f4 __attribute__((ext_vector_type(4)));

// ---------------------------------------------------------------------------
// Kernel 1: projections k|v|q = x @ [Wk|Wv|Wq].
// 512 blocks x 512 threads (8 waves). Block owns PR=8 x-rows staged once in
// 32 KB LDS. Wave wv covers K-slice c in [128wv, 128wv+128); lane = output d.
// Per thread: 8-row register blocking -> 24 FMAs per 3 W loads (W L2 traffic
// ~395 MB total). Cross-wave K-reduction via LDS (buffer reused from x panel,
// two phases so 4x1536 partials fit in the same 32 KB).
// k stored transposed kT[d][row] for coalesced attn phase-1.
// ---------------------------------------------------------------------------
__global__ __launch_bounds__(512) void proj_kernel(
    const float* __restrict__ x,
    const float* __restrict__ Wk,
    const float* __restrict__ Wv,
    const float* __restrict__ Wq,
    float* __restrict__ kT,     // [DD][NROW]
    float* __restrict__ vbuf,   // [NROW][DD]
    float* __restrict__ qbuf)   // [BB*TT][DD]
{
    __shared__ __align__(16) float smem[PR * CC];   // 32 KB; later red[4][1536]

    const int tid  = threadIdx.x;
    const int lane = tid & 63;
    const int wv   = tid >> 6;              // 0..7
    const int bs0  = blockIdx.x * PR;
    const int nr   = (NROW - bs0 < PR) ? (NROW - bs0) : PR;
    const int s0   = bs0 % SS;
    const bool needq = (s0 + PR - 1) >= (TT - 1);

    // ---- stage x panel: 8 rows x 1024 floats, coalesced f4 ----
    {
        const f4* xg = (const f4*)x;
        f4* xs4 = (f4*)smem;
#pragma unroll
        for (int j = 0; j < 4; ++j) {
            const int idx = tid + j * 512;         // 0..2047
            const int r = idx >> 8, c4 = idx & 255;
            int g = bs0 + r; if (g > NROW - 1) g = NROW - 1;
            xs4[idx] = xg[(size_t)g * (CC / 4) + c4];
        }
    }
    __syncthreads();

    float accK[PR], accV[PR], accQ[PR];
#pragma unroll
    for (int r = 0; r < PR; ++r) { accK[r] = 0.f; accV[r] = 0.f; accQ[r] = 0.f; }

    const int c0 = wv * 128;
    const float* wkp = Wk + (size_t)c0 * DD + lane;
    const float* wvp = Wv + (size_t)c0 * DD + lane;
    const float* wqp = Wq + (size_t)c0 * DD + lane;

    for (int c4 = 0; c4 < 32; ++c4) {
        f4 xv[PR];
#pragma unroll
        for (int r = 0; r < PR; ++r)
            xv[r] = *(const f4*)&smem[r * CC + c0 + c4 * 4];
#pragma unroll
        for (int kk = 0; kk < 4; ++kk) {
            const int cl = c4 * 4 + kk;
            const float wk = wkp[cl * DD];
            const float wl = wvp[cl * DD];
#pragma unroll
            for (int r = 0; r < PR; ++r) {
                accK[r] = fmaf(xv[r][kk], wk, accK[r]);
                accV[r] = fmaf(xv[r][kk], wl, accV[r]);
            }
            if (needq) {
                const float wq = wqp[cl * DD];
#pragma unroll
                for (int r = 0; r < PR; ++r)
                    accQ[r] = fmaf(xv[r][kk], wq, accQ[r]);
            }
        }
    }
    __syncthreads();            // x panel no longer needed -> reuse as red

    // ---- cross-wave reduction: red[4][1536], waves 4-7 add onto 0-3 ----
    float* red = smem;
    const int base = (wv & 3) * 1536;
    if (wv < 4) {
#pragma unroll
        for (int r = 0; r < PR; ++r) {
            red[base + lane * PR + r]        = accK[r];   // k: [d][r]
            red[base + 512 + r * DD + lane]  = accV[r];   // v: [r][d]
        }
        if (needq)
#pragma unroll
            for (int r = 0; r < PR; ++r)
                red[base + 1024 + r * DD + lane] = accQ[r];
    }
    __syncthreads();
    if (wv >= 4) {
#pragma unroll
        for (int r = 0; r < PR; ++r) {
            red[base + lane * PR + r]       += accK[r];
            red[base + 512 + r * DD + lane] += accV[r];
        }
        if (needq)
#pragma unroll
            for (int r = 0; r < PR; ++r)
                red[base + 1024 + r * DD + lane] += accQ[r];
    }
    __syncthreads();

    // ---- final 4-way sum + stores ----
    const int nslots = needq ? 1536 : 1024;
    for (int slot = tid; slot < nslots; slot += 512) {
        const float s = red[slot] + red[slot + 1536] +
                        red[slot + 3072] + red[slot + 4608];
        if (slot < 512) {
            const int dd = slot >> 3, r = slot & 7;
            if (r < nr) kT[(size_t)dd * NROW + bs0 + r] = s;
        } else if (slot < 1024) {
            const int i = slot - 512, r = i >> 6, dd = i & 63;
            if (r < nr) vbuf[(size_t)(bs0 + r) * DD + dd] = s;
        } else {
            const int i = slot - 1024, r = i >> 6, dd = i & 63;
            if (r < nr) {
                const int bs = bs0 + r;
                const int b = bs / SS, ss = bs - b * SS;
                if (ss >= TT - 1)
                    qbuf[((size_t)b * TT + (ss - (TT - 1))) * DD + dd] = s;
            }
        }
    }
}

// ---------------------------------------------------------------------------
// Kernel 2: attention per (b, w) — 2048 blocks x 256 threads (occupancy
// regime that worked in round 2), now with coalesced kT reads and bias
// folded into the logit FMA.
// ---------------------------------------------------------------------------
__global__ __launch_bounds__(256) void attn_kernel(
    const float* __restrict__ kT,     // [DD][NROW]
    const float* __restrict__ vbuf,   // [NROW][DD]
    const float* __restrict__ qbuf,   // [BB*TT][DD]
    const float* __restrict__ bias,   // [DD][TT]
    float* __restrict__ out)          // [BB*TT][DD]
{
    __shared__ float qs[DD];
    __shared__ float wei[TT];
    __shared__ float red[8];
    __shared__ float partial[4][DD];

    const int bw  = blockIdx.x;
    const int b   = bw >> 9;
    const int w   = bw & (TT - 1);
    const int tid = threadIdx.x;
    const int wave = tid >> 6;
    const int lane = tid & 63;

    if (tid < DD) qs[tid] = qbuf[(size_t)bw * DD + tid];
    __syncthreads();

    // ---- phase 1: logits, coalesced in t ----
    const float* kcol = kT + (size_t)b * SS + w;
    float acc0 = 0.f, acc1 = 0.f;
#pragma unroll 4
    for (int dd = 0; dd < DD; ++dd) {
        const float q  = qs[dd];
        const float k0 = kcol[(size_t)dd * NROW + tid];
        const float k1 = kcol[(size_t)dd * NROW + tid + 256];
        const float b0 = bias[dd * TT + tid];
        const float b1 = bias[dd * TT + tid + 256];
        acc0 = fmaf(q, k0 + b0, acc0);
        acc1 = fmaf(q, k1 + b1, acc1);
    }

    // ---- block max ----
    float m = fmaxf(acc0, acc1);
#pragma unroll
    for (int off = 32; off; off >>= 1)
        m = fmaxf(m, __shfl_down(m, off, 64));
    if (lane == 0) red[wave] = m;
    __syncthreads();
    m = fmaxf(fmaxf(red[0], red[1]), fmaxf(red[2], red[3]));

    // ---- exp + block sum ----
    const float e0 = __expf(acc0 - m);
    const float e1 = __expf(acc1 - m);
    wei[tid]       = e0;
    wei[tid + 256] = e1;
    float ssum = e0 + e1;
#pragma unroll
    for (int off = 32; off; off >>= 1)
        ssum += __shfl_down(ssum, off, 64);
    if (lane == 0) red[4 + wave] = ssum;
    __syncthreads();
    const float inv = 1.f / (red[4] + red[5] + red[6] + red[7]);

    // ---- phase 2: out[d] = sum_t wei[t] * v[b, w+t, d]  (coalesced) ----
    {
        const int dd = lane;
        float a = 0.f;
        const float* vbase = vbuf + ((size_t)(b * SS + w)) * DD + dd;
        const int t0 = wave * 128;
#pragma unroll 4
        for (int t = t0; t < t0 + 128; ++t)
            a = fmaf(wei[t], vbase[(size_t)t * DD], a);
        partial[wave][dd] = a;
    }
    __syncthreads();

    if (tid < DD) {
        const float o = (partial[0][tid] + partial[1][tid] +
                         partial[2][tid] + partial[3][tid]) * inv;
        out[(size_t)bw * DD + tid] = o;
    }
}

// ---------------------------------------------------------------------------
extern "C" void kernel_launch(void* const* d_in, const int* in_sizes, int n_in,
                              void* d_out, int out_size, void* d_ws, size_t ws_size,
                              hipStream_t stream) {
    const float* x    = (const float*)d_in[0];
    const float* Wk   = (const float*)d_in[1];
    const float* Wv   = (const float*)d_in[2];
    const float* Wq   = (const float*)d_in[3];
    const float* bias = (const float*)d_in[4];
    float* out = (float*)d_out;

    float* kT   = (float*)d_ws;                     // DD*NROW
    float* vbuf = kT + (size_t)DD * NROW;           // NROW*DD
    float* qbuf = vbuf + (size_t)NROW * DD;         // BB*TT*DD

    proj_kernel<<<PBLOCKS, 512, 0, stream>>>(x, Wk, Wv, Wq, kT, vbuf, qbuf);
    attn_kernel<<<BB * TT, 256, 0, stream>>>(kT, vbuf, qbuf, bias, out);
}